// Round 3
// baseline (946.709 us; speedup 1.0000x reference)
//
#include <hip/hip_runtime.h>
#include <cstdint>
#include <cstddef>

#define NPTS 500000

using f16   = _Float16;
using f16x8 = __attribute__((ext_vector_type(8))) _Float16;
using f32x4 = __attribute__((ext_vector_type(4))) float;
using f32x16= __attribute__((ext_vector_type(16))) float;

// ---- ws layout (bytes): f16 weight images, pre-transposed W^T[m][k], output rows
// phi-permuted (phi = swap bits 2<->3 of m), XOR-swizzled rows; then f32 bias image.
#define WS_INW   0u           // 128 rows x 512B (K=256)
#define WS_SKIP  65536u       // 4 x 65536
#define WS_W1    327680u      // 8 x 32768 (K=128, 256B pitch)
#define WS_W2    589824u      // 8 x 32768
#define WS_BIAS  851968u      // 22*128 f32: arr[M][pos] = b_M[phi(pos)]
#define WS_BC    863232u      // 8*2*16 f32: B coeffs prescaled by 1/(2pi)
#define WS_OB    864256u      // 1 f32 + pad
#define WS_TOTAL 864272u

__device__ __host__ __forceinline__ int phi(int m) {
  return (m & ~12) | ((m & 4) << 1) | ((m & 8) >> 1);
}
// XOR swizzle: pitch 256B rows have 16 16B-slots (mask 15), pitch 512B rows 32 (mask 31).
// Read-side and pack-side (prep) must use the same mask per image.
__device__ __forceinline__ uint32_t swz(uint32_t off, uint32_t row, uint32_t mask) {
  return off ^ ((row & mask) << 4);
}

// ---------------- prep: pack everything into ws
extern "C" __global__ void pinn_prep(const float* __restrict__ in_w,
                                     const float* __restrict__ w1,
                                     const float* __restrict__ w2,
                                     const float* __restrict__ skw,
                                     const float* __restrict__ inb,
                                     const float* __restrict__ b1,
                                     const float* __restrict__ b2,
                                     const float* __restrict__ skb,
                                     const float* __restrict__ ow,
                                     const float* __restrict__ ob,
                                     const float* __restrict__ Bg,
                                     char* __restrict__ ws) {
  int idx = (int)blockIdx.x * 256 + (int)threadIdx.x;
  if (idx < 32768) {                       // in_wT: [128 m][256 k], phi rows
    int m = idx >> 8, k = idx & 255;
    uint32_t off = swz((uint32_t)(m * 512 + k * 2), (uint32_t)m, 31u);
    *(f16*)(ws + WS_INW + off) = (f16)in_w[k * 128 + phi(m)];
  } else if (idx < 163840) {               // skip_wT[j]
    int r = idx - 32768; int j = r >> 15; r &= 32767;
    int m = r >> 8, k = r & 255;
    uint32_t off = swz((uint32_t)(m * 512 + k * 2), (uint32_t)m, 31u);
    *(f16*)(ws + WS_SKIP + (uint32_t)j * 65536u + off) = (f16)skw[(j * 256 + k) * 128 + phi(m)];
  } else if (idx < 425984) {               // w1T / w2T
    int r = idx - 163840;
    const int isw2 = (r >= 131072);
    int rr = r & 131071;
    int i = rr >> 14; int q = rr & 16383;
    int m = q >> 7, k = q & 127;
    uint32_t off = swz((uint32_t)(m * 256 + k * 2), (uint32_t)m, 15u);
    uint32_t base = (isw2 ? WS_W2 : WS_W1) + (uint32_t)i * 32768u;
    const float* src = isw2 ? w2 : w1;
    *(f16*)(ws + base + off) = (f16)src[(i * 128 + k) * 128 + phi(m)];
  } else if (idx < 428800) {               // bias image
    int r = idx - 425984;
    int M = r >> 7, pos = r & 127;
    int pp = phi(pos);
    float v;
    if (M == 0)        v = inb[pp];
    else if (M <= 16)  { int t = M - 1; int i = t >> 1; v = (t & 1) ? b2[i * 128 + pp] : b1[i * 128 + pp]; }
    else if (M <= 20)  v = skb[(M - 17) * 128 + pp];
    else               v = ow[pp];
    *(float*)(ws + WS_BIAS + (uint32_t)r * 4u) = v;
  } else if (idx < 429056) {               // Bc coeffs
    int r = idx - 428800;
    int slot = r >> 4, e2 = r & 15;
    int kq = slot >> 1, hb = slot & 1;
    int row = e2 >> 3, e = e2 & 7;
    int j = kq * 16 + hb * 8 + e;
    *(float*)(ws + WS_BC + (uint32_t)r * 4u) = Bg[row * 128 + j] * 0.15915494309189535f;
  } else if (idx == 429056) {
    *(float*)(ws + WS_OB) = ob[0];
    *(float*)(ws + WS_OB + 4) = 0.f; *(float*)(ws + WS_OB + 8) = 0.f; *(float*)(ws + WS_OB + 12) = 0.f;
  }
}

// ---------------- device math
__device__ __forceinline__ float ftanh(float x) {
  float e = __builtin_amdgcn_exp2f(x * 2.8853901817f);
  return 1.0f - 2.0f * __builtin_amdgcn_rcpf(e + 1.0f);
}
__device__ __forceinline__ float fsin_rev(float rev) {
  return __builtin_amdgcn_sinf(__builtin_amdgcn_fractf(rev));
}

// async global->LDS, 16B per lane
__device__ __forceinline__ void gll16(const char* g, char* l) {
  __builtin_amdgcn_global_load_lds((const __attribute__((address_space(1))) void*)g,
                                   (__attribute__((address_space(3))) void*)l, 16, 0, 0);
}
__device__ __forceinline__ void stage64(const char* g, char* l, int wv, int ln64) {
  const char* gs = g + wv * 8192 + ln64 * 16;
  char* ls = l + wv * 8192;
  #pragma unroll
  for (int it = 0; it < 8; ++it) gll16(gs + it * 1024, ls + it * 1024);
}
__device__ __forceinline__ void stage32(const char* g, char* l, int wv, int ln64) {
  const char* gs = g + wv * 4096 + ln64 * 16;
  char* ls = l + wv * 4096;
  #pragma unroll
  for (int it = 0; it < 4; ++it) gll16(gs + it * 1024, ls + it * 1024);
}

#define MFMA_(a,b,c) __builtin_amdgcn_mfma_f32_32x32x16_f16(a,b,c,0,0,0)

#define BINIT(acc, Mi, MT) { const float* _bp = biasL + ((Mi)*128 + (MT)*32 + hi4); \
  f32x4 _q0 = *(const f32x4*)_bp;        f32x4 _q1 = *(const f32x4*)(_bp+8); \
  f32x4 _q2 = *(const f32x4*)(_bp+16);   f32x4 _q3 = *(const f32x4*)(_bp+24); \
  acc[0]=_q0[0]; acc[1]=_q0[1]; acc[2]=_q0[2]; acc[3]=_q0[3]; \
  acc[4]=_q1[0]; acc[5]=_q1[1]; acc[6]=_q1[2]; acc[7]=_q1[3]; \
  acc[8]=_q2[0]; acc[9]=_q2[1]; acc[10]=_q2[2]; acc[11]=_q2[3]; \
  acc[12]=_q3[0]; acc[13]=_q3[1]; acc[14]=_q3[2]; acc[15]=_q3[3]; }

#define UNPADD(acc, F0, F1) { \
  acc[0]+=(float)F0[0]; acc[1]+=(float)F0[1]; acc[2]+=(float)F0[2]; acc[3]+=(float)F0[3]; \
  acc[4]+=(float)F0[4]; acc[5]+=(float)F0[5]; acc[6]+=(float)F0[6]; acc[7]+=(float)F0[7]; \
  acc[8]+=(float)F1[0]; acc[9]+=(float)F1[1]; acc[10]+=(float)F1[2]; acc[11]+=(float)F1[3]; \
  acc[12]+=(float)F1[4]; acc[13]+=(float)F1[5]; acc[14]+=(float)F1[6]; acc[15]+=(float)F1[7]; }

#define FPACK(F0, F1, acc) { f16x8 _g0, _g1; \
  _g0[0]=(f16)acc[0]; _g0[1]=(f16)acc[1]; _g0[2]=(f16)acc[2]; _g0[3]=(f16)acc[3]; \
  _g0[4]=(f16)acc[4]; _g0[5]=(f16)acc[5]; _g0[6]=(f16)acc[6]; _g0[7]=(f16)acc[7]; \
  _g1[0]=(f16)acc[8]; _g1[1]=(f16)acc[9]; _g1[2]=(f16)acc[10]; _g1[3]=(f16)acc[11]; \
  _g1[4]=(f16)acc[12]; _g1[5]=(f16)acc[13]; _g1[6]=(f16)acc[14]; _g1[7]=(f16)acc[15]; \
  F0=_g0; F1=_g1; }

#define TPACK(F0, F1, acc) { f16x8 _g0, _g1; \
  _g0[0]=(f16)ftanh(acc[0]); _g0[1]=(f16)ftanh(acc[1]); _g0[2]=(f16)ftanh(acc[2]); _g0[3]=(f16)ftanh(acc[3]); \
  _g0[4]=(f16)ftanh(acc[4]); _g0[5]=(f16)ftanh(acc[5]); _g0[6]=(f16)ftanh(acc[6]); _g0[7]=(f16)ftanh(acc[7]); \
  _g1[0]=(f16)ftanh(acc[8]); _g1[1]=(f16)ftanh(acc[9]); _g1[2]=(f16)ftanh(acc[10]); _g1[3]=(f16)ftanh(acc[11]); \
  _g1[4]=(f16)ftanh(acc[12]); _g1[5]=(f16)ftanh(acc[13]); _g1[6]=(f16)ftanh(acc[14]); _g1[7]=(f16)ftanh(acc[15]); \
  F0=_g0; F1=_g1; }

#define OM2PI 4.7746482927f
#define SINPACK(F0, F1, acc) { f16x8 _g0, _g1; \
  _g0[0]=(f16)fsin_rev(acc[0]*OM2PI); _g0[1]=(f16)fsin_rev(acc[1]*OM2PI); \
  _g0[2]=(f16)fsin_rev(acc[2]*OM2PI); _g0[3]=(f16)fsin_rev(acc[3]*OM2PI); \
  _g0[4]=(f16)fsin_rev(acc[4]*OM2PI); _g0[5]=(f16)fsin_rev(acc[5]*OM2PI); \
  _g0[6]=(f16)fsin_rev(acc[6]*OM2PI); _g0[7]=(f16)fsin_rev(acc[7]*OM2PI); \
  _g1[0]=(f16)fsin_rev(acc[8]*OM2PI); _g1[1]=(f16)fsin_rev(acc[9]*OM2PI); \
  _g1[2]=(f16)fsin_rev(acc[10]*OM2PI); _g1[3]=(f16)fsin_rev(acc[11]*OM2PI); \
  _g1[4]=(f16)fsin_rev(acc[12]*OM2PI); _g1[5]=(f16)fsin_rev(acc[13]*OM2PI); \
  _g1[6]=(f16)fsin_rev(acc[14]*OM2PI); _g1[7]=(f16)fsin_rev(acc[15]*OM2PI); \
  F0=_g0; F1=_g1; }

#define W1K(kb) { f16x8 _a = *(const f16x8*)(wb + swz(_m*256u + kb*32u + hi16, lnr, 15u)); \
  acc0 = MFMA_(_a, xA##kb, acc0); acc1 = MFMA_(_a, xB##kb, acc1); }
#define W2K(kb) { f16x8 _a = *(const f16x8*)(wb2 + swz(_m*256u + kb*32u + hi16, lnr, 15u)); \
  acc0 = MFMA_(_a, uA##kb, acc0); acc1 = MFMA_(_a, uB##kb, acc1); }
#define SKK(kb) { f16x8 _a = *(const f16x8*)(sb_ + swz(_m*512u + kb*32u + hi16, lnr, 31u)); \
  acc = MFMA_(_a, fr##kb, acc); }

#define W1TILE(MT, UA0_, UA1_, UB0_, UB1_) { const uint32_t _m = MT*32u + lnr; \
  f32x16 acc0; BINIT(acc0, Mw1, MT); f32x16 acc1 = acc0; \
  W1K(0) W1K(1) W1K(2) W1K(3) W1K(4) W1K(5) W1K(6) W1K(7) \
  TPACK(UA0_, UA1_, acc0); TPACK(UB0_, UB1_, acc1); }

#define W2TILE(MT, XA0_, XA1_, XB0_, XB1_) { const uint32_t _m = MT*32u + lnr; \
  f32x16 acc0; BINIT(acc0, Mw2, MT); f32x16 acc1 = acc0; \
  UNPADD(acc0, XA0_, XA1_); UNPADD(acc1, XB0_, XB1_); \
  W2K(0) W2K(1) W2K(2) W2K(3) W2K(4) W2K(5) W2K(6) W2K(7) \
  FPACK(XA0_, XA1_, acc0); FPACK(XB0_, XB1_, acc1); }

#define SKTILE(MT, X0_, X1_, MI) { const uint32_t _m = MT*32u + lnr; \
  f32x16 acc; BINIT(acc, MI, MT); UNPADD(acc, X0_, X1_); \
  SKK(0) SKK(1) SKK(2) SKK(3) SKK(4) SKK(5) SKK(6) SKK(7) \
  SKK(8) SKK(9) SKK(10) SKK(11) SKK(12) SKK(13) SKK(14) SKK(15) \
  FPACK(X0_, X1_, acc); }

#define INTILE(MT, X0_, X1_) { const uint32_t _m = MT*32u + lnr; \
  f32x16 acc; BINIT(acc, 0, MT); \
  SKK(0) SKK(1) SKK(2) SKK(3) SKK(4) SKK(5) SKK(6) SKK(7) \
  SKK(8) SKK(9) SKK(10) SKK(11) SKK(12) SKK(13) SKK(14) SKK(15) \
  SINPACK(X0_, X1_, acc); }

#define FFE(ei, C0, C1) { float _rv = __builtin_amdgcn_fractf(sS*(C0) + tT*(C1)); \
  _fs[ei] = (f16)__builtin_amdgcn_sinf(_rv); _fc[ei] = (f16)__builtin_amdgcn_cosf(_rv); }
#define FFKQ(KQ, FS, FC) { const float* _cp = BcL + (KQ*2+hi)*16; \
  f32x4 _a0 = *(const f32x4*)_cp, _a1 = *(const f32x4*)(_cp+4); \
  f32x4 _b0 = *(const f32x4*)(_cp+8), _b1 = *(const f32x4*)(_cp+12); \
  f16x8 _fs, _fc; \
  FFE(0,_a0[0],_b0[0]) FFE(1,_a0[1],_b0[1]) FFE(2,_a0[2],_b0[2]) FFE(3,_a0[3],_b0[3]) \
  FFE(4,_a1[0],_b1[0]) FFE(5,_a1[1],_b1[1]) FFE(6,_a1[2],_b1[2]) FFE(7,_a1[3],_b1[3]) \
  FS = _fs; FC = _fc; }
#define FFALL() FFKQ(0,fr0,fr8) FFKQ(1,fr1,fr9) FFKQ(2,fr2,fr10) FFKQ(3,fr3,fr11) \
                FFKQ(4,fr4,fr12) FFKQ(5,fr5,fr13) FFKQ(6,fr6,fr14) FFKQ(7,fr7,fr15)

#define OWDOT(P, F0, F1, bp) P += (float)F0[0]*bp[0] + (float)F0[1]*bp[1] + (float)F0[2]*bp[2] + (float)F0[3]*bp[3] \
  + (float)F0[4]*bp[8]  + (float)F0[5]*bp[9]  + (float)F0[6]*bp[10] + (float)F0[7]*bp[11] \
  + (float)F1[0]*bp[16] + (float)F1[1]*bp[17] + (float)F1[2]*bp[18] + (float)F1[3]*bp[19] \
  + (float)F1[4]*bp[24] + (float)F1[5]*bp[25] + (float)F1[6]*bp[26] + (float)F1[7]*bp[27];

// ---------------- main: 512 threads = 8 independent waves, 64 pts/wave (2 nt x 32)
// Activations live entirely in registers as f16 MFMA fragments (phi-layout identity).
// amdgpu_waves_per_eu(2,2): dynamic LDS (143KB) already caps us at 1 block/CU = 2
// waves/SIMD; pin the compiler's occupancy target there so it uses the full
// 256-reg budget instead of capping at 128 and spilling (R2: 1.3GB scratch traffic).
extern "C" __global__ void __launch_bounds__(512)
__attribute__((amdgpu_waves_per_eu(2, 2))) pinn_main(
    const float* __restrict__ Sg, const float* __restrict__ Tg,
    const char* __restrict__ ws, float* __restrict__ outg)
{
  extern __shared__ char smem[];                 // buf0 64K | buf1 64K | bias 12.3K
  const float* biasL = (const float*)(smem + 131072);
  const float* BcL   = biasL + 2816;

  const int tid  = (int)threadIdx.x;
  const int lane = tid & 63;
  const int wave = tid >> 6;
  const int hi   = lane >> 5;
  const uint32_t lnr = (uint32_t)(lane & 31);
  const uint32_t hi16 = (uint32_t)hi * 16u;
  const int hi4  = hi * 4;
  const int blk0 = (int)blockIdx.x * 512;

  // point coords (issued early; clamped tail)
  const int pb = blk0 + wave * 64 + (int)lnr;
  const int q0 = pb      < NPTS ? pb      : NPTS - 1;
  const int q1 = pb + 32 < NPTS ? pb + 32 : NPTS - 1;
  const float s0v = Sg[q0], t0v = Tg[q0];
  const float s1v = Sg[q1], t1v = Tg[q1];

  // stage bias image (plain copy) + in_w (async) -> buf0
  #pragma unroll 1
  for (int o = tid * 16; o < 12304; o += 8192)
    *(f32x4*)(smem + 131072 + o) = *(const f32x4*)(ws + WS_BIAS + o);
  stage64(ws + WS_INW, smem, wave, lane);
  __syncthreads();

  // master fragments (x) and u fragments — all named registers
  f16x8 xA0,xA1,xA2,xA3,xA4,xA5,xA6,xA7, xB0,xB1,xB2,xB3,xB4,xB5,xB6,xB7;
  f16x8 uA0,uA1,uA2,uA3,uA4,uA5,uA6,uA7, uB0,uB1,uB2,uB3,uB4,uB5,uB6,uB7;

  // prefetch w12_0 -> buf1 while computing input layer
  stage32(ws + WS_W1, smem + 65536, wave, lane);
  stage32(ws + WS_W2, smem + 65536 + 32768, wave, lane);

  // ---- input layer: x = sin(30*(ff @ in_w + in_b)), reads buf0
  { const float sS = s0v, tT = t0v;
    const char* sb_ = smem;
    f16x8 fr0,fr1,fr2,fr3,fr4,fr5,fr6,fr7,fr8,fr9,fr10,fr11,fr12,fr13,fr14,fr15;
    FFALL()
    INTILE(0, xA0, xA1) INTILE(1, xA2, xA3) INTILE(2, xA4, xA5) INTILE(3, xA6, xA7)
  }
  { const float sS = s1v, tT = t1v;
    const char* sb_ = smem;
    f16x8 fr0,fr1,fr2,fr3,fr4,fr5,fr6,fr7,fr8,fr9,fr10,fr11,fr12,fr13,fr14,fr15;
    FFALL()
    INTILE(0, xB0, xB1) INTILE(1, xB2, xB3) INTILE(2, xB4, xB5) INTILE(3, xB6, xB7)
  }
  __syncthreads();

  // ---- residual blocks
  #pragma unroll 1
  for (int i = 0; i < 8; ++i) {
    const int wbix = ((i >> 1) & 1) ^ 1;           // w12_i buffer
    const char* wb  = smem + wbix * 65536;
    const char* wb2 = wb + 32768;
    const int Mw1 = 1 + 2 * i, Mw2 = 2 + 2 * i;

    // prefetch next image
    if ((i & 1) == 0) {
      const int j = i >> 1;
      stage64(ws + WS_SKIP + (uint32_t)j * 65536u, smem + (j & 1) * 65536, wave, lane);
    } else if (i < 7) {
      const int bix = (((i + 1) >> 1) & 1) ^ 1;
      stage32(ws + WS_W1 + (uint32_t)(i + 1) * 32768u, smem + bix * 65536, wave, lane);
      stage32(ws + WS_W2 + (uint32_t)(i + 1) * 32768u, smem + bix * 65536 + 32768, wave, lane);
    }

    // u = tanh(x@w1 + b1)
    W1TILE(0, uA0, uA1, uB0, uB1)
    W1TILE(1, uA2, uA3, uB2, uB3)
    W1TILE(2, uA4, uA5, uB4, uB5)
    W1TILE(3, uA6, uA7, uB6, uB7)
    // x = x + u@w2 + b2
    W2TILE(0, xA0, xA1, xB0, xB1)
    W2TILE(1, xA2, xA3, xB2, xB3)
    W2TILE(2, xA4, xA5, xB4, xB5)
    W2TILE(3, xA6, xA7, xB6, xB7)
    __syncthreads();

    if ((i & 1) == 0) {                            // skip phase (reads buf[(i/2)&1])
      const int j = i >> 1;
      const int bix2 = (((i + 1) >> 1) & 1) ^ 1;   // prefetch w12_{i+1}
      stage32(ws + WS_W1 + (uint32_t)(i + 1) * 32768u, smem + bix2 * 65536, wave, lane);
      stage32(ws + WS_W2 + (uint32_t)(i + 1) * 32768u, smem + bix2 * 65536 + 32768, wave, lane);
      const int Msk = 17 + j;
      { const float sS = s0v, tT = t0v;
        const char* sb_ = smem + (j & 1) * 65536;
        f16x8 fr0,fr1,fr2,fr3,fr4,fr5,fr6,fr7,fr8,fr9,fr10,fr11,fr12,fr13,fr14,fr15;
        FFALL()
        SKTILE(0, xA0, xA1, Msk) SKTILE(1, xA2, xA3, Msk)
        SKTILE(2, xA4, xA5, Msk) SKTILE(3, xA6, xA7, Msk)
      }
      { const float sS = s1v, tT = t1v;
        const char* sb_ = smem + (j & 1) * 65536;
        f16x8 fr0,fr1,fr2,fr3,fr4,fr5,fr6,fr7,fr8,fr9,fr10,fr11,fr12,fr13,fr14,fr15;
        FFALL()
        SKTILE(0, xB0, xB1, Msk) SKTILE(1, xB2, xB3, Msk)
        SKTILE(2, xB4, xB5, Msk) SKTILE(3, xB6, xB7, Msk)
      }
      __syncthreads();
    }
  }

  // ---- output: out = x @ out_w + out_b
  float p0 = 0.0f, p1 = 0.0f;
  { const float* bp = biasL + 21 * 128 + 0 * 32 + hi4; OWDOT(p0, xA0, xA1, bp) OWDOT(p1, xB0, xB1, bp) }
  { const float* bp = biasL + 21 * 128 + 1 * 32 + hi4; OWDOT(p0, xA2, xA3, bp) OWDOT(p1, xB2, xB3, bp) }
  { const float* bp = biasL + 21 * 128 + 2 * 32 + hi4; OWDOT(p0, xA4, xA5, bp) OWDOT(p1, xB4, xB5, bp) }
  { const float* bp = biasL + 21 * 128 + 3 * 32 + hi4; OWDOT(p0, xA6, xA7, bp) OWDOT(p1, xB6, xB7, bp) }
  p0 += __shfl_xor(p0, 32);
  p1 += __shfl_xor(p1, 32);
  const float obv = biasL[3072];
  if (hi == 0) {
    if (pb < NPTS)      outg[pb]      = p0 + obv;
    if (pb + 32 < NPTS) outg[pb + 32] = p1 + obv;
  }
}

extern "C" void kernel_launch(void* const* d_in, const int* in_sizes, int n_in,
                              void* d_out, int out_size, void* d_ws, size_t ws_size,
                              hipStream_t stream) {
  (void)in_sizes; (void)n_in; (void)out_size;
  const float* S   = (const float*)d_in[0];
  const float* T   = (const float*)d_in[1];
  const float* B   = (const float*)d_in[2];
  const float* inw = (const float*)d_in[3];
  const float* inb = (const float*)d_in[4];
  const float* w1  = (const float*)d_in[5];
  const float* b1  = (const float*)d_in[6];
  const float* w2  = (const float*)d_in[7];
  const float* b2  = (const float*)d_in[8];
  const float* sw  = (const float*)d_in[9];
  const float* sb  = (const float*)d_in[10];
  const float* ow  = (const float*)d_in[11];
  const float* ob  = (const float*)d_in[12];
  char* ws   = (char*)d_ws;
  float* out = (float*)d_out;
  if (ws_size < (size_t)WS_TOTAL) return;

  pinn_prep<<<1677, 256, 0, stream>>>(inw, w1, w2, sw, inb, b1, b2, sb, ow, ob, B, ws);

  const int smem_bytes = 143376;
  hipFuncSetAttribute(reinterpret_cast<const void*>(pinn_main),
                      hipFuncAttributeMaxDynamicSharedMemorySize, smem_bytes);
  const int grid = (NPTS + 511) / 512;   // 977
  pinn_main<<<grid, 512, smem_bytes, stream>>>(S, T, ws, out);
}

// Round 4
// 577.809 us; speedup vs baseline: 1.6384x; 1.6384x over previous
//
#include <hip/hip_runtime.h>
#include <cstdint>
#include <cstddef>

#define NPTS 500000

using f16   = _Float16;
using f16x8 = __attribute__((ext_vector_type(8))) _Float16;
using f32x4 = __attribute__((ext_vector_type(4))) float;
using f32x16= __attribute__((ext_vector_type(16))) float;

// ---- ws layout (bytes): f16 weight images, pre-transposed W^T[m][k], output rows
// phi-permuted (phi = swap bits 2<->3 of m), XOR-swizzled rows; then f32 bias image.
// in_w / skip_w images use K-INTERLEAVED columns: slice kb=2g holds sin-weights of
// j-group g (j = g*16..g*16+15), slice kb=2g+1 the cos-weights of the same group.
#define WS_INW   0u           // 128 rows x 512B (K=256)
#define WS_SKIP  65536u       // 4 x 65536
#define WS_W1    327680u      // 8 x 32768 (K=128, 256B pitch)
#define WS_W2    589824u      // 8 x 32768
#define WS_BIAS  851968u      // 22*128 f32: arr[M][pos] = b_M[phi(pos)]
#define WS_BC    863232u      // 8*2*16 f32: B coeffs prescaled by 1/(2pi)
#define WS_OB    864256u      // 1 f32 + pad
#define WS_TOTAL 864272u

__device__ __host__ __forceinline__ int phi(int m) {
  return (m & ~12) | ((m & 4) << 1) | ((m & 8) >> 1);
}
// XOR swizzle: pitch 256B rows have 16 16B-slots (mask 15), pitch 512B rows 32 (mask 31).
__device__ __forceinline__ uint32_t swz(uint32_t off, uint32_t row, uint32_t mask) {
  return off ^ ((row & mask) << 4);
}

// ---------------- prep: pack everything into ws
extern "C" __global__ void pinn_prep(const float* __restrict__ in_w,
                                     const float* __restrict__ w1,
                                     const float* __restrict__ w2,
                                     const float* __restrict__ skw,
                                     const float* __restrict__ inb,
                                     const float* __restrict__ b1,
                                     const float* __restrict__ b2,
                                     const float* __restrict__ skb,
                                     const float* __restrict__ ow,
                                     const float* __restrict__ ob,
                                     const float* __restrict__ Bg,
                                     char* __restrict__ ws) {
  int idx = (int)blockIdx.x * 256 + (int)threadIdx.x;
  if (idx < 32768) {                       // in_wT: [128 m][256 c], interleaved K
    int m = idx >> 8, c = idx & 255;
    int k = ((c >> 4) & 1) * 128 + (c >> 5) * 16 + (c & 15);
    uint32_t off = swz((uint32_t)(m * 512 + c * 2), (uint32_t)m, 31u);
    *(f16*)(ws + WS_INW + off) = (f16)in_w[k * 128 + phi(m)];
  } else if (idx < 163840) {               // skip_wT[j], interleaved K
    int r = idx - 32768; int j = r >> 15; r &= 32767;
    int m = r >> 8, c = r & 255;
    int k = ((c >> 4) & 1) * 128 + (c >> 5) * 16 + (c & 15);
    uint32_t off = swz((uint32_t)(m * 512 + c * 2), (uint32_t)m, 31u);
    *(f16*)(ws + WS_SKIP + (uint32_t)j * 65536u + off) = (f16)skw[(j * 256 + k) * 128 + phi(m)];
  } else if (idx < 425984) {               // w1T / w2T
    int r = idx - 163840;
    const int isw2 = (r >= 131072);
    int rr = r & 131071;
    int i = rr >> 14; int q = rr & 16383;
    int m = q >> 7, k = q & 127;
    uint32_t off = swz((uint32_t)(m * 256 + k * 2), (uint32_t)m, 15u);
    uint32_t base = (isw2 ? WS_W2 : WS_W1) + (uint32_t)i * 32768u;
    const float* src = isw2 ? w2 : w1;
    *(f16*)(ws + base + off) = (f16)src[(i * 128 + k) * 128 + phi(m)];
  } else if (idx < 428800) {               // bias image
    int r = idx - 425984;
    int M = r >> 7, pos = r & 127;
    int pp = phi(pos);
    float v;
    if (M == 0)        v = inb[pp];
    else if (M <= 16)  { int t = M - 1; int i = t >> 1; v = (t & 1) ? b2[i * 128 + pp] : b1[i * 128 + pp]; }
    else if (M <= 20)  v = skb[(M - 17) * 128 + pp];
    else               v = ow[pp];
    *(float*)(ws + WS_BIAS + (uint32_t)r * 4u) = v;
  } else if (idx < 429056) {               // Bc coeffs: slot (g, hi): b0[j..j+8), b1[j..j+8)
    int r = idx - 428800;
    int slot = r >> 4, e2 = r & 15;
    int kq = slot >> 1, hb = slot & 1;
    int row = e2 >> 3, e = e2 & 7;
    int j = kq * 16 + hb * 8 + e;
    *(float*)(ws + WS_BC + (uint32_t)r * 4u) = Bg[row * 128 + j] * 0.15915494309189535f;
  } else if (idx == 429056) {
    *(float*)(ws + WS_OB) = ob[0];
    *(float*)(ws + WS_OB + 4) = 0.f; *(float*)(ws + WS_OB + 8) = 0.f; *(float*)(ws + WS_OB + 12) = 0.f;
  }
}

// ---------------- device math
__device__ __forceinline__ float ftanh(float x) {
  float e = __builtin_amdgcn_exp2f(x * 2.8853901817f);
  return 1.0f - 2.0f * __builtin_amdgcn_rcpf(e + 1.0f);
}
__device__ __forceinline__ float fsin_rev(float rev) {
  return __builtin_amdgcn_sinf(__builtin_amdgcn_fractf(rev));
}

// async global->LDS, 16B per lane
__device__ __forceinline__ void gll16(const char* g, char* l) {
  __builtin_amdgcn_global_load_lds((const __attribute__((address_space(1))) void*)g,
                                   (__attribute__((address_space(3))) void*)l, 16, 0, 0);
}
__device__ __forceinline__ void stage64(const char* g, char* l, int wv, int ln64) {
  const char* gs = g + wv * 8192 + ln64 * 16;
  char* ls = l + wv * 8192;
  #pragma unroll
  for (int it = 0; it < 8; ++it) gll16(gs + it * 1024, ls + it * 1024);
}
__device__ __forceinline__ void stage32(const char* g, char* l, int wv, int ln64) {
  const char* gs = g + wv * 4096 + ln64 * 16;
  char* ls = l + wv * 4096;
  #pragma unroll
  for (int it = 0; it < 4; ++it) gll16(gs + it * 1024, ls + it * 1024);
}

#define MFMA_(a,b,c) __builtin_amdgcn_mfma_f32_32x32x16_f16(a,b,c,0,0,0)

// LDS fragment loads (A-operand, weight images)
#define LD256(BASE, MT, KB) (*(const f16x8*)((BASE) + \
  swz(((uint32_t)(MT)*32u + lnr)*256u + (uint32_t)(KB)*32u + hi16, lnr, 15u)))
#define LD512(BASE, MT, KB) (*(const f16x8*)((BASE) + \
  swz(((uint32_t)(MT)*32u + lnr)*512u + (uint32_t)(KB)*32u + hi16, lnr, 31u)))

#define BINIT(acc, Mi, MT) { const float* _bp = biasL + ((Mi)*128 + (MT)*32 + hi4); \
  f32x4 _q0 = *(const f32x4*)_bp;        f32x4 _q1 = *(const f32x4*)(_bp+8); \
  f32x4 _q2 = *(const f32x4*)(_bp+16);   f32x4 _q3 = *(const f32x4*)(_bp+24); \
  acc[0]=_q0[0]; acc[1]=_q0[1]; acc[2]=_q0[2]; acc[3]=_q0[3]; \
  acc[4]=_q1[0]; acc[5]=_q1[1]; acc[6]=_q1[2]; acc[7]=_q1[3]; \
  acc[8]=_q2[0]; acc[9]=_q2[1]; acc[10]=_q2[2]; acc[11]=_q2[3]; \
  acc[12]=_q3[0]; acc[13]=_q3[1]; acc[14]=_q3[2]; acc[15]=_q3[3]; }

#define UNPADD(acc, F0, F1) { \
  acc[0]+=(float)F0[0]; acc[1]+=(float)F0[1]; acc[2]+=(float)F0[2]; acc[3]+=(float)F0[3]; \
  acc[4]+=(float)F0[4]; acc[5]+=(float)F0[5]; acc[6]+=(float)F0[6]; acc[7]+=(float)F0[7]; \
  acc[8]+=(float)F1[0]; acc[9]+=(float)F1[1]; acc[10]+=(float)F1[2]; acc[11]+=(float)F1[3]; \
  acc[12]+=(float)F1[4]; acc[13]+=(float)F1[5]; acc[14]+=(float)F1[6]; acc[15]+=(float)F1[7]; }

#define FPACK(F0, F1, acc) { f16x8 _g0, _g1; \
  _g0[0]=(f16)acc[0]; _g0[1]=(f16)acc[1]; _g0[2]=(f16)acc[2]; _g0[3]=(f16)acc[3]; \
  _g0[4]=(f16)acc[4]; _g0[5]=(f16)acc[5]; _g0[6]=(f16)acc[6]; _g0[7]=(f16)acc[7]; \
  _g1[0]=(f16)acc[8]; _g1[1]=(f16)acc[9]; _g1[2]=(f16)acc[10]; _g1[3]=(f16)acc[11]; \
  _g1[4]=(f16)acc[12]; _g1[5]=(f16)acc[13]; _g1[6]=(f16)acc[14]; _g1[7]=(f16)acc[15]; \
  F0=_g0; F1=_g1; }

#define TPACK(F0, F1, acc) { f16x8 _g0, _g1; \
  _g0[0]=(f16)ftanh(acc[0]); _g0[1]=(f16)ftanh(acc[1]); _g0[2]=(f16)ftanh(acc[2]); _g0[3]=(f16)ftanh(acc[3]); \
  _g0[4]=(f16)ftanh(acc[4]); _g0[5]=(f16)ftanh(acc[5]); _g0[6]=(f16)ftanh(acc[6]); _g0[7]=(f16)ftanh(acc[7]); \
  _g1[0]=(f16)ftanh(acc[8]); _g1[1]=(f16)ftanh(acc[9]); _g1[2]=(f16)ftanh(acc[10]); _g1[3]=(f16)ftanh(acc[11]); \
  _g1[4]=(f16)ftanh(acc[12]); _g1[5]=(f16)ftanh(acc[13]); _g1[6]=(f16)ftanh(acc[14]); _g1[7]=(f16)ftanh(acc[15]); \
  F0=_g0; F1=_g1; }

#define OM2PI 4.7746482927f
#define SINPACK(F0, F1, acc) { f16x8 _g0, _g1; \
  _g0[0]=(f16)fsin_rev(acc[0]*OM2PI); _g0[1]=(f16)fsin_rev(acc[1]*OM2PI); \
  _g0[2]=(f16)fsin_rev(acc[2]*OM2PI); _g0[3]=(f16)fsin_rev(acc[3]*OM2PI); \
  _g0[4]=(f16)fsin_rev(acc[4]*OM2PI); _g0[5]=(f16)fsin_rev(acc[5]*OM2PI); \
  _g0[6]=(f16)fsin_rev(acc[6]*OM2PI); _g0[7]=(f16)fsin_rev(acc[7]*OM2PI); \
  _g1[0]=(f16)fsin_rev(acc[8]*OM2PI); _g1[1]=(f16)fsin_rev(acc[9]*OM2PI); \
  _g1[2]=(f16)fsin_rev(acc[10]*OM2PI); _g1[3]=(f16)fsin_rev(acc[11]*OM2PI); \
  _g1[4]=(f16)fsin_rev(acc[12]*OM2PI); _g1[5]=(f16)fsin_rev(acc[13]*OM2PI); \
  _g1[6]=(f16)fsin_rev(acc[14]*OM2PI); _g1[7]=(f16)fsin_rev(acc[15]*OM2PI); \
  F0=_g0; F1=_g1; }

// Fourier pair for group g, BOTH point groups (coeffs loaded once, shared)
#define FFE(ei, CA, CB) { \
  float _r0 = __builtin_amdgcn_fractf(s0v*(CA) + t0v*(CB)); \
  _s0[ei]=(f16)__builtin_amdgcn_sinf(_r0); _c0[ei]=(f16)__builtin_amdgcn_cosf(_r0); \
  float _r1 = __builtin_amdgcn_fractf(s1v*(CA) + t1v*(CB)); \
  _s1[ei]=(f16)__builtin_amdgcn_sinf(_r1); _c1[ei]=(f16)__builtin_amdgcn_cosf(_r1); }
#define FF2(G, FSA, FCA, FSB, FCB) { const float* _cp = BcL + ((G)*2+hi)*16; \
  f32x4 _a0 = *(const f32x4*)_cp, _a1 = *(const f32x4*)(_cp+4); \
  f32x4 _b0 = *(const f32x4*)(_cp+8), _b1 = *(const f32x4*)(_cp+12); \
  f16x8 _s0, _c0, _s1, _c1; \
  FFE(0,_a0[0],_b0[0]) FFE(1,_a0[1],_b0[1]) FFE(2,_a0[2],_b0[2]) FFE(3,_a0[3],_b0[3]) \
  FFE(4,_a1[0],_b1[0]) FFE(5,_a1[1],_b1[1]) FFE(6,_a1[2],_b1[2]) FFE(7,_a1[3],_b1[3]) \
  FSA=_s0; FCA=_c0; FSB=_s1; FCB=_c1; }

// K=256 ff-matmul half-pass over two mtiles (M0_, M1_): fr-pair streaming (8+8 regs)
// + 4 accs (64 regs). A-frag reuse x2 (both point groups). DOIN: BINIT-only vs
// UNPADD(residual); EPI: SINPACK vs FPACK.
#define FFPASS(M0_, M1_, MI_, XA0,XA1, XB0,XB1, YA0,YA1, YB0,YB1, RES, SINEPI) { \
  f32x16 a00; BINIT(a00, MI_, M0_); f32x16 a01 = a00; \
  f32x16 a10; BINIT(a10, MI_, M1_); f32x16 a11 = a10; \
  if (RES) { UNPADD(a00, XA0, XA1) UNPADD(a01, XB0, XB1) \
             UNPADD(a10, YA0, YA1) UNPADD(a11, YB0, YB1) } \
  for (int g = 0; g < 8; ++g) { \
    f16x8 fsA, fcA, fsB, fcB; \
    FF2(g, fsA, fcA, fsB, fcB) \
    { f16x8 _w = LD512(sb_, M0_, 2*g);   a00 = MFMA_(_w, fsA, a00); a01 = MFMA_(_w, fsB, a01); } \
    { f16x8 _w = LD512(sb_, M0_, 2*g+1); a00 = MFMA_(_w, fcA, a00); a01 = MFMA_(_w, fcB, a01); } \
    { f16x8 _w = LD512(sb_, M1_, 2*g);   a10 = MFMA_(_w, fsA, a10); a11 = MFMA_(_w, fsB, a11); } \
    { f16x8 _w = LD512(sb_, M1_, 2*g+1); a10 = MFMA_(_w, fcA, a10); a11 = MFMA_(_w, fcB, a11); } \
  } \
  if (SINEPI) { SINPACK(XA0, XA1, a00) SINPACK(XB0, XB1, a01) \
                SINPACK(YA0, YA1, a10) SINPACK(YB0, YB1, a11) } \
  else        { FPACK(XA0, XA1, a00) FPACK(XB0, XB1, a01) \
                FPACK(YA0, YA1, a10) FPACK(YB0, YB1, a11) } }

#define W1K(kb) { f16x8 _a = LD256(wb, MTv, kb); \
  acc0 = MFMA_(_a, xA##kb, acc0); acc1 = MFMA_(_a, xB##kb, acc1); }
#define W2K(kb) { f16x8 _a = LD256(wb2, MTv, kb); \
  acc0 = MFMA_(_a, uA##kb, acc0); acc1 = MFMA_(_a, uB##kb, acc1); }

#define W1TILE(MT, UA0_, UA1_, UB0_, UB1_) { const uint32_t MTv = (MT); \
  f32x16 acc0; BINIT(acc0, Mw1, MT); f32x16 acc1 = acc0; \
  W1K(0) W1K(1) W1K(2) W1K(3) W1K(4) W1K(5) W1K(6) W1K(7) \
  TPACK(UA0_, UA1_, acc0); TPACK(UB0_, UB1_, acc1); }

#define W2TILE(MT, XA0_, XA1_, XB0_, XB1_) { const uint32_t MTv = (MT); \
  f32x16 acc0; BINIT(acc0, Mw2, MT); f32x16 acc1 = acc0; \
  UNPADD(acc0, XA0_, XA1_); UNPADD(acc1, XB0_, XB1_); \
  W2K(0) W2K(1) W2K(2) W2K(3) W2K(4) W2K(5) W2K(6) W2K(7) \
  FPACK(XA0_, XA1_, acc0); FPACK(XB0_, XB1_, acc1); }

#define OWDOT(P, F0, F1, bp) P += (float)F0[0]*bp[0] + (float)F0[1]*bp[1] + (float)F0[2]*bp[2] + (float)F0[3]*bp[3] \
  + (float)F0[4]*bp[8]  + (float)F0[5]*bp[9]  + (float)F0[6]*bp[10] + (float)F0[7]*bp[11] \
  + (float)F1[0]*bp[16] + (float)F1[1]*bp[17] + (float)F1[2]*bp[18] + (float)F1[3]*bp[19] \
  + (float)F1[4]*bp[24] + (float)F1[5]*bp[25] + (float)F1[6]*bp[26] + (float)F1[7]*bp[27];

// ---------------- main: 512 threads = 8 independent waves, 64 pts/wave (2 x 32)
// Activations live entirely in registers as f16 MFMA fragments (phi-layout identity).
// Explicit backend attrs (R3: allocator clamped arch VGPRs at 128 -> 650MB spill
// round-trip). flat_work_group_size fixes block shape; waves_per_eu(2,2) pins the
// occupancy target at 2/SIMD (the dynamic-LDS 143KB already caps us there).
extern "C" __global__ void
__attribute__((amdgpu_flat_work_group_size(512, 512), amdgpu_waves_per_eu(2, 2)))
pinn_main(const float* __restrict__ Sg, const float* __restrict__ Tg,
          const char* __restrict__ ws, float* __restrict__ outg)
{
  extern __shared__ char smem[];                 // buf0 64K | buf1 64K | bias 12.3K
  const float* biasL = (const float*)(smem + 131072);
  const float* BcL   = biasL + 2816;

  const int tid  = (int)threadIdx.x;
  const int lane = tid & 63;
  const int wave = tid >> 6;
  const int hi   = lane >> 5;
  const uint32_t lnr = (uint32_t)(lane & 31);
  const uint32_t hi16 = (uint32_t)hi * 16u;
  const int hi4  = hi * 4;
  const int blk0 = (int)blockIdx.x * 512;

  // point coords (issued early; clamped tail)
  const int pb = blk0 + wave * 64 + (int)lnr;
  const int q0 = pb      < NPTS ? pb      : NPTS - 1;
  const int q1 = pb + 32 < NPTS ? pb + 32 : NPTS - 1;
  const float s0v = Sg[q0], t0v = Tg[q0];
  const float s1v = Sg[q1], t1v = Tg[q1];

  // stage bias image (plain copy) + in_w (async) -> buf0
  #pragma unroll 1
  for (int o = tid * 16; o < 12304; o += 8192)
    *(f32x4*)(smem + 131072 + o) = *(const f32x4*)(ws + WS_BIAS + o);
  stage64(ws + WS_INW, smem, wave, lane);
  __syncthreads();

  // master fragments (x) and u fragments — all named registers
  f16x8 xA0,xA1,xA2,xA3,xA4,xA5,xA6,xA7, xB0,xB1,xB2,xB3,xB4,xB5,xB6,xB7;
  f16x8 uA0,uA1,uA2,uA3,uA4,uA5,uA6,uA7, uB0,uB1,uB2,uB3,uB4,uB5,uB6,uB7;

  // prefetch w12_0 -> buf1 while computing input layer
  stage32(ws + WS_W1, smem + 65536, wave, lane);
  stage32(ws + WS_W2, smem + 65536 + 32768, wave, lane);

  // ---- input layer: x = sin(30*(ff @ in_w + in_b)), reads buf0; two half-passes
  {
    const char* sb_ = smem;
    FFPASS(0, 1, 0, xA0,xA1, xB0,xB1, xA2,xA3, xB2,xB3, 0, 1)
    FFPASS(2, 3, 0, xA4,xA5, xB4,xB5, xA6,xA7, xB6,xB7, 0, 1)
  }
  __syncthreads();

  // ---- residual blocks
  #pragma unroll 1
  for (int i = 0; i < 8; ++i) {
    const int wbix = ((i >> 1) & 1) ^ 1;           // w12_i buffer
    const char* wb  = smem + wbix * 65536;
    const char* wb2 = wb + 32768;
    const int Mw1 = 1 + 2 * i, Mw2 = 2 + 2 * i;

    // prefetch next image
    if ((i & 1) == 0) {
      const int j = i >> 1;
      stage64(ws + WS_SKIP + (uint32_t)j * 65536u, smem + (j & 1) * 65536, wave, lane);
    } else if (i < 7) {
      const int bix = (((i + 1) >> 1) & 1) ^ 1;
      stage32(ws + WS_W1 + (uint32_t)(i + 1) * 32768u, smem + bix * 65536, wave, lane);
      stage32(ws + WS_W2 + (uint32_t)(i + 1) * 32768u, smem + bix * 65536 + 32768, wave, lane);
    }

    // u = tanh(x@w1 + b1)
    W1TILE(0, uA0, uA1, uB0, uB1)
    W1TILE(1, uA2, uA3, uB2, uB3)
    W1TILE(2, uA4, uA5, uB4, uB5)
    W1TILE(3, uA6, uA7, uB6, uB7)
    // x = x + u@w2 + b2
    W2TILE(0, xA0, xA1, xB0, xB1)
    W2TILE(1, xA2, xA3, xB2, xB3)
    W2TILE(2, xA4, xA5, xB4, xB5)
    W2TILE(3, xA6, xA7, xB6, xB7)
    __syncthreads();

    if ((i & 1) == 0) {                            // skip phase (reads buf[(i/2)&1])
      const int j = i >> 1;
      const int bix2 = (((i + 1) >> 1) & 1) ^ 1;   // prefetch w12_{i+1}
      stage32(ws + WS_W1 + (uint32_t)(i + 1) * 32768u, smem + bix2 * 65536, wave, lane);
      stage32(ws + WS_W2 + (uint32_t)(i + 1) * 32768u, smem + bix2 * 65536 + 32768, wave, lane);
      const int Msk = 17 + j;
      const char* sb_ = smem + (j & 1) * 65536;
      FFPASS(0, 1, Msk, xA0,xA1, xB0,xB1, xA2,xA3, xB2,xB3, 1, 0)
      FFPASS(2, 3, Msk, xA4,xA5, xB4,xB5, xA6,xA7, xB6,xB7, 1, 0)
      __syncthreads();
    }
  }

  // ---- output: out = x @ out_w + out_b
  float p0 = 0.0f, p1 = 0.0f;
  { const float* bp = biasL + 21 * 128 + 0 * 32 + hi4; OWDOT(p0, xA0, xA1, bp) OWDOT(p1, xB0, xB1, bp) }
  { const float* bp = biasL + 21 * 128 + 1 * 32 + hi4; OWDOT(p0, xA2, xA3, bp) OWDOT(p1, xB2, xB3, bp) }
  { const float* bp = biasL + 21 * 128 + 2 * 32 + hi4; OWDOT(p0, xA4, xA5, bp) OWDOT(p1, xB4, xB5, bp) }
  { const float* bp = biasL + 21 * 128 + 3 * 32 + hi4; OWDOT(p0, xA6, xA7, bp) OWDOT(p1, xB6, xB7, bp) }
  p0 += __shfl_xor(p0, 32);
  p1 += __shfl_xor(p1, 32);
  const float obv = biasL[3072];
  if (hi == 0) {
    if (pb < NPTS)      outg[pb]      = p0 + obv;
    if (pb + 32 < NPTS) outg[pb + 32] = p1 + obv;
  }
}

extern "C" void kernel_launch(void* const* d_in, const int* in_sizes, int n_in,
                              void* d_out, int out_size, void* d_ws, size_t ws_size,
                              hipStream_t stream) {
  (void)in_sizes; (void)n_in; (void)out_size;
  const float* S   = (const float*)d_in[0];
  const float* T   = (const float*)d_in[1];
  const float* B   = (const float*)d_in[2];
  const float* inw = (const float*)d_in[3];
  const float* inb = (const float*)d_in[4];
  const float* w1  = (const float*)d_in[5];
  const float* b1  = (const float*)d_in[6];
  const float* w2  = (const float*)d_in[7];
  const float* b2  = (const float*)d_in[8];
  const float* sw  = (const float*)d_in[9];
  const float* sb  = (const float*)d_in[10];
  const float* ow  = (const float*)d_in[11];
  const float* ob  = (const float*)d_in[12];
  char* ws   = (char*)d_ws;
  float* out = (float*)d_out;
  if (ws_size < (size_t)WS_TOTAL) return;

  pinn_prep<<<1677, 256, 0, stream>>>(inw, w1, w2, sw, inb, b1, b2, sb, ow, ob, B, ws);

  const int smem_bytes = 143376;
  hipFuncSetAttribute(reinterpret_cast<const void*>(pinn_main),
                      hipFuncAttributeMaxDynamicSharedMemorySize, smem_bytes);
  const int grid = (NPTS + 511) / 512;   // 977
  pinn_main<<<grid, 512, smem_bytes, stream>>>(S, T, ws, out);
}